// Round 4
// baseline (215.795 us; speedup 1.0000x reference)
//
#include <hip/hip_runtime.h>
#include <hip/hip_cooperative_groups.h>

namespace cg = cooperative_groups;

typedef int v4i __attribute__((ext_vector_type(4)));

#define IN_DIM  8192
#define OUT_DIM 28672
#define NS      32              // super-steps: 4 k-steps = 1KB/row each

// pack low bytes of 4 int32 lanes -> one dword (3x v_perm_b32)
static __device__ __forceinline__ unsigned pack_lo_bytes(v4i q) {
  unsigned t0 = __builtin_amdgcn_perm((unsigned)q.y, (unsigned)q.x, 0x00000400u);
  unsigned t1 = __builtin_amdgcn_perm((unsigned)q.w, (unsigned)q.z, 0x00000400u);
  return __builtin_amdgcn_perm(t1, t0, 0x05040100u);
}

// issue the 16 weight loads of one super-step: 1KB contiguous per row, ascending addresses
static __device__ __forceinline__ void issue_w(v4i (&dst)[16], const char* wpb, int s) {
  const char* bp = wpb + (size_t)s * 1024;
#pragma unroll
  for (int kk2 = 0; kk2 < 4; ++kk2)
#pragma unroll
    for (int p = 0; p < 4; ++p)
      dst[kk2*4 + p] = *(const v4i*)(bp + kk2*256 + p*64);
}

static __device__ __forceinline__ void compute_ss(
    const v4i (&src)[16], int s,
    const unsigned char* x1p, const unsigned char* x2p,
    v4i& acc1, v4i& acc2) {
#pragma unroll
  for (int kk2 = 0; kk2 < 4; ++kk2) {
    const int kk = s*4 + kk2;
    const v4i xa = *(const v4i*)(x1p + (size_t)kk * 1024);
    const v4i xb = *(const v4i*)(x2p + (size_t)kk * 1024);
    v4i bw;
    bw.x = (int)pack_lo_bytes(src[kk2*4 + 0]);
    bw.y = (int)pack_lo_bytes(src[kk2*4 + 1]);
    bw.z = (int)pack_lo_bytes(src[kk2*4 + 2]);
    bw.w = (int)pack_lo_bytes(src[kk2*4 + 3]);
    acc1 = __builtin_amdgcn_mfma_i32_16x16x64_i8(xa, bw, acc1, 0, 0, 0);
    acc2 = __builtin_amdgcn_mfma_i32_16x16x64_i8(xb, bw, acc2, 0, 0, 0);
  }
}

// ---- fused cooperative kernel: 256 blocks x 7 waves ----
// phase 0: all waves issue 2 weight super-steps (HBM stream starts immediately)
// phase 1: wave 0 of blocks 0..15 quantizes x row b (2-level int8, MFMA-A-order)
// grid.sync(); phase 2: R3 main loop with 3-buffer rotation (2KB/row in flight)
__global__ __launch_bounds__(448, 2) void qgemm_fused(
    const float* __restrict__ x,
    const int* __restrict__ w,
    const float* __restrict__ wscaler,
    unsigned char* __restrict__ q1p,
    unsigned char* __restrict__ q2p,
    float* __restrict__ scales,
    float* __restrict__ out)
{
  const int lane = threadIdx.x & 63;
  const int wv   = threadIdx.x >> 6;        // 0..6
  const int col  = lane & 15;
  const int grp  = lane >> 4;
  const int o    = blockIdx.x * 112 + wv * 16 + col;

  const char* wpb = (const char*)(w + (size_t)o * IN_DIM) + grp * 16;

  v4i wa[16], wb[16], wc[16];
  issue_w(wa, wpb, 0);
  issue_w(wb, wpb, 1);

  // ---- quant phase (streaming, ~no register footprint) ----
  if (blockIdx.x < 16 && wv == 0) {
    const int b = blockIdx.x;
    const float* xr = x + (size_t)b * IN_DIM;
    // pass 1: row absmax (coalesced float4)
    float m = 0.0f;
    for (int i = lane; i < IN_DIM/4; i += 64) {
      float4 f = ((const float4*)xr)[i];
      m = fmaxf(m, fmaxf(fmaxf(fabsf(f.x), fabsf(f.y)), fmaxf(fabsf(f.z), fabsf(f.w))));
    }
#pragma unroll
    for (int off = 32; off >= 1; off >>= 1)
      m = fmaxf(m, __shfl_xor(m, off));
    m = fmaxf(m, 1e-20f);
    const float s1   = m * (1.0f / 127.0f);
    const float inv1 = 1.0f / s1;
    const float s2   = s1 * (1.0f / 254.0f);
    const float inv2 = 1.0f / s2;
    if (lane == 0) { scales[b] = s1; scales[16 + b] = s2; }
    // pass 2: quantize lane's k-range [lane*128, lane*128+128) (L2-hot reload)
    // byte (b,k) lives at kk*1024 + grp*256 + b*16 + d*4 + j, k = kk*64+d*16+grp*4+j
#pragma unroll
    for (int kk2 = 0; kk2 < 2; ++kk2) {
      const int kk = lane * 2 + kk2;
      const float* xs = xr + kk * 64;
      unsigned char* c1 = q1p + kk * 1024 + b * 16;
      unsigned char* c2 = q2p + kk * 1024 + b * 16;
#pragma unroll
      for (int d = 0; d < 4; ++d) {
#pragma unroll
        for (int g = 0; g < 4; ++g) {
          unsigned a1 = 0, a2 = 0;
#pragma unroll
          for (int j = 0; j < 4; ++j) {
            const float xv = xs[d*16 + g*4 + j];
            float q1 = rintf(xv * inv1);
            q1 = fminf(127.0f, fmaxf(-127.0f, q1));
            const float r = fmaf(-s1, q1, xv);
            float q2 = rintf(r * inv2);
            q2 = fminf(127.0f, fmaxf(-127.0f, q2));
            a1 |= ((unsigned)((int)q1 & 0xff)) << (8*j);
            a2 |= ((unsigned)((int)q2 & 0xff)) << (8*j);
          }
          *(unsigned*)(c1 + g*256 + d*4) = a1;
          *(unsigned*)(c2 + g*256 + d*4) = a2;
        }
      }
    }
    __threadfence();
  }
  cg::this_grid().sync();

  // ---- main loop: 3-buffer rotation, 32 = 3*10 + 2 ----
  const unsigned char* x1p = q1p + lane * 16;
  const unsigned char* x2p = q2p + lane * 16;
  v4i acc1 = {0,0,0,0}, acc2 = {0,0,0,0};

  for (int j = 0; j < 10; ++j) {
    const int s = j * 3;
    compute_ss(wa, s,     x1p, x2p, acc1, acc2);  issue_w(wc, wpb, s + 2);
    compute_ss(wb, s + 1, x1p, x2p, acc1, acc2);  issue_w(wa, wpb, s + 3);
    compute_ss(wc, s + 2, x1p, x2p, acc1, acc2);  issue_w(wb, wpb, s + 4);
  }
  compute_ss(wa, 30, x1p, x2p, acc1, acc2);
  compute_ss(wb, 31, x1p, x2p, acc1, acc2);

  // epilogue: C/D layout col=lane&15, row=(lane>>4)*4+reg
  const float sc = wscaler[o];
#pragma unroll
  for (int r = 0; r < 4; ++r) {
    const int b = grp * 4 + r;
    const float val = scales[b] * (float)acc1[r] + scales[16 + b] * (float)acc2[r];
    out[(size_t)b * OUT_DIM + o] = val * sc;
  }
}

extern "C" void kernel_launch(void* const* d_in, const int* in_sizes, int n_in,
                              void* d_out, int out_size, void* d_ws, size_t ws_size,
                              hipStream_t stream) {
  const float* x       = (const float*)d_in[0];
  const int*   w       = (const int*)d_in[1];     // int8 values stored as int32
  const float* wscaler = (const float*)d_in[2];
  float* out = (float*)d_out;

  unsigned char* ws  = (unsigned char*)d_ws;
  unsigned char* q1p = ws;                        // 128 KiB
  unsigned char* q2p = ws + 131072;               // 128 KiB
  float* scales      = (float*)(ws + 262144);     // 32 floats

  void* args[] = { (void*)&x, (void*)&w, (void*)&wscaler,
                   (void*)&q1p, (void*)&q2p, (void*)&scales, (void*)&out };
  hipLaunchCooperativeKernel((const void*)qgemm_fused,
                             dim3(256), dim3(448), args, 0, stream);
}

// Round 5
// 182.207 us; speedup vs baseline: 1.1843x; 1.1843x over previous
//
#include <hip/hip_runtime.h>

typedef int v4i __attribute__((ext_vector_type(4)));

#define B_DIM   16
#define IN_DIM  8192
#define OUT_DIM 28672
#define NS      32              // super-steps (4 k-steps = 1KB/row each)

// pack low bytes of 4 int32 lanes -> one dword (3x v_perm_b32)
static __device__ __forceinline__ unsigned pack_lo_bytes(v4i q) {
  unsigned t0 = __builtin_amdgcn_perm((unsigned)q.y, (unsigned)q.x, 0x00000400u);
  unsigned t1 = __builtin_amdgcn_perm((unsigned)q.w, (unsigned)q.z, 0x00000400u);
  return __builtin_amdgcn_perm(t1, t0, 0x05040100u);
}

// ---- pre-pass: per-row 2-level int8 quantization of x, packed in MFMA A-fragment order ----
// k = kk*64 + d*16 + grp*4 + j lives at kk*1024 + grp*256 + b*16 + d*4 + j.
// B-side uses the same (grp,d,j)->k map, so the MFMA k-slot permutation cancels exactly.
__global__ __launch_bounds__(256) void xquant_kernel(
    const float* __restrict__ x,
    unsigned char* __restrict__ q1p,
    unsigned char* __restrict__ q2p,
    float* __restrict__ scales)
{
  const int b   = blockIdx.x;
  const int tid = threadIdx.x;
  const float* xr = x + (size_t)b * IN_DIM + tid * 32;

  float v[32];
  float m = 0.0f;
#pragma unroll
  for (int i = 0; i < 8; ++i) {
    float4 f = ((const float4*)xr)[i];
    v[i*4+0] = f.x; v[i*4+1] = f.y; v[i*4+2] = f.z; v[i*4+3] = f.w;
    m = fmaxf(m, fmaxf(fmaxf(fabsf(f.x), fabsf(f.y)), fmaxf(fabsf(f.z), fabsf(f.w))));
  }
#pragma unroll
  for (int off = 32; off >= 1; off >>= 1)
    m = fmaxf(m, __shfl_xor(m, off));
  __shared__ float lmax[4];
  if ((tid & 63) == 0) lmax[tid >> 6] = m;
  __syncthreads();
  m = fmaxf(fmaxf(lmax[0], lmax[1]), fmaxf(lmax[2], lmax[3]));
  m = fmaxf(m, 1e-20f);

  const float s1   = m * (1.0f / 127.0f);
  const float inv1 = 1.0f / s1;
  const float s2   = s1 * (1.0f / 254.0f);
  const float inv2 = 1.0f / s2;
  if (tid == 0) { scales[b] = s1; scales[16 + b] = s2; }

  const int kk = tid >> 1, h2 = tid & 1;
  unsigned char* b1 = q1p + kk * 1024 + b * 16 + h2 * 8;
  unsigned char* b2 = q2p + kk * 1024 + b * 16 + h2 * 8;
#pragma unroll
  for (int i16 = 0; i16 < 2; ++i16) {
#pragma unroll
    for (int grp = 0; grp < 4; ++grp) {
      unsigned a1 = 0, a2 = 0;
#pragma unroll
      for (int j = 0; j < 4; ++j) {
        const float xv = v[i16*16 + grp*4 + j];
        float q1 = rintf(xv * inv1);
        q1 = fminf(127.0f, fmaxf(-127.0f, q1));
        const float r = fmaf(-s1, q1, xv);
        float q2 = rintf(r * inv2);
        q2 = fminf(127.0f, fmaxf(-127.0f, q2));
        a1 |= ((unsigned)((int)q1 & 0xff)) << (8*j);
        a2 |= ((unsigned)((int)q2 & 0xff)) << (8*j);
      }
      *(unsigned*)(b1 + grp*256 + i16*4) = a1;
      *(unsigned*)(b2 + grp*256 + i16*4) = a2;
    }
  }
}

// issue the 16 weight loads of one super-step: 1KB contiguous per row, ascending
// addresses, nontemporal (read-once stream -> don't evict q1p/q2p from L2)
static __device__ __forceinline__ void issue_w(v4i (&dst)[16], const char* wpb, int s) {
  const char* bp = wpb + (size_t)s * 1024;
#pragma unroll
  for (int kk2 = 0; kk2 < 4; ++kk2)
#pragma unroll
    for (int p = 0; p < 4; ++p)
      dst[kk2*4 + p] = __builtin_nontemporal_load((const v4i*)(bp + kk2*256 + p*64));
}

static __device__ __forceinline__ void compute_ss(
    const v4i (&src)[16], int s,
    const unsigned char* x1p, const unsigned char* x2p,
    v4i& acc1, v4i& acc2) {
#pragma unroll
  for (int kk2 = 0; kk2 < 4; ++kk2) {
    const int kk = s*4 + kk2;
    const v4i xa = *(const v4i*)(x1p + (size_t)kk * 1024);
    const v4i xb = *(const v4i*)(x2p + (size_t)kk * 1024);
    v4i bw;
    bw.x = (int)pack_lo_bytes(src[kk2*4 + 0]);
    bw.y = (int)pack_lo_bytes(src[kk2*4 + 1]);
    bw.z = (int)pack_lo_bytes(src[kk2*4 + 2]);
    bw.w = (int)pack_lo_bytes(src[kk2*4 + 3]);
    acc1 = __builtin_amdgcn_mfma_i32_16x16x64_i8(xa, bw, acc1, 0, 0, 0);
    acc2 = __builtin_amdgcn_mfma_i32_16x16x64_i8(xb, bw, acc2, 0, 0, 0);
  }
}

// ---- main GEMM: 256 blocks x 7 waves; wave = 16 output channels over full K ----
// 3-buffer register rotation: 3KB/row window, ~2KB steady-state in flight.
__global__ __launch_bounds__(448, 2) void qgemm_kernel(
    const int* __restrict__ w,
    const unsigned char* __restrict__ q1p,
    const unsigned char* __restrict__ q2p,
    const float* __restrict__ scales,
    const float* __restrict__ wscaler,
    float* __restrict__ out)
{
  const int lane = threadIdx.x & 63;
  const int wv   = threadIdx.x >> 6;        // 0..6
  const int col  = lane & 15;
  const int grp  = lane >> 4;
  const int o    = blockIdx.x * 112 + wv * 16 + col;

  const char* wpb = (const char*)(w + (size_t)o * IN_DIM) + grp * 16;
  const unsigned char* x1p = q1p + lane * 16;
  const unsigned char* x2p = q2p + lane * 16;

  v4i acc1 = {0,0,0,0}, acc2 = {0,0,0,0};
  v4i wa[16], wb[16], wc[16];

  issue_w(wa, wpb, 0);
  issue_w(wb, wpb, 1);
  issue_w(wc, wpb, 2);

  for (int j = 0; j < 9; ++j) {
    const int s = j * 3;
    compute_ss(wa, s,     x1p, x2p, acc1, acc2);  issue_w(wa, wpb, s + 3);
    compute_ss(wb, s + 1, x1p, x2p, acc1, acc2);  issue_w(wb, wpb, s + 4);
    compute_ss(wc, s + 2, x1p, x2p, acc1, acc2);  issue_w(wc, wpb, s + 5);
  }
  compute_ss(wa, 27, x1p, x2p, acc1, acc2);  issue_w(wa, wpb, 30);
  compute_ss(wb, 28, x1p, x2p, acc1, acc2);  issue_w(wb, wpb, 31);
  compute_ss(wc, 29, x1p, x2p, acc1, acc2);
  compute_ss(wa, 30, x1p, x2p, acc1, acc2);
  compute_ss(wb, 31, x1p, x2p, acc1, acc2);

  // epilogue: C/D layout col=lane&15, row=(lane>>4)*4+reg
  const float sc = wscaler[o];
#pragma unroll
  for (int r = 0; r < 4; ++r) {
    const int b = grp * 4 + r;
    const float val = scales[b] * (float)acc1[r] + scales[16 + b] * (float)acc2[r];
    out[(size_t)b * OUT_DIM + o] = val * sc;
  }
}

extern "C" void kernel_launch(void* const* d_in, const int* in_sizes, int n_in,
                              void* d_out, int out_size, void* d_ws, size_t ws_size,
                              hipStream_t stream) {
  const float* x       = (const float*)d_in[0];
  const int*   w       = (const int*)d_in[1];     // int8 values stored as int32
  const float* wscaler = (const float*)d_in[2];
  float* out = (float*)d_out;

  unsigned char* ws  = (unsigned char*)d_ws;
  unsigned char* q1p = ws;                        // 128 KiB
  unsigned char* q2p = ws + 131072;               // 128 KiB
  float* scales      = (float*)(ws + 262144);     // 32 floats

  xquant_kernel<<<16, 256, 0, stream>>>(x, q1p, q2p, scales);
  qgemm_kernel<<<256, 448, 0, stream>>>(w, q1p, q2p, scales, wscaler, out);
}

// Round 6
// 174.425 us; speedup vs baseline: 1.2372x; 1.0446x over previous
//
#include <hip/hip_runtime.h>

typedef int v4i __attribute__((ext_vector_type(4)));

#define B_DIM   16
#define IN_DIM  8192
#define OUT_DIM 28672
#define NS      32              // super-steps (4 k-steps = 1KB/row each)

// pack low bytes of 4 int32 lanes -> one dword (3x v_perm_b32)
static __device__ __forceinline__ unsigned pack_lo_bytes(v4i q) {
  unsigned t0 = __builtin_amdgcn_perm((unsigned)q.y, (unsigned)q.x, 0x00000400u);
  unsigned t1 = __builtin_amdgcn_perm((unsigned)q.w, (unsigned)q.z, 0x00000400u);
  return __builtin_amdgcn_perm(t1, t0, 0x05040100u);
}

// ---- pre-pass: per-row 2-level int8 quantization of x, packed in MFMA A-fragment order ----
// k = kk*64 + d*16 + grp*4 + j lives at kk*1024 + grp*256 + b*16 + d*4 + j.
// B-side uses the same (grp,d,j)->k map, so the MFMA k-slot permutation cancels exactly.
__global__ __launch_bounds__(256) void xquant_kernel(
    const float* __restrict__ x,
    unsigned char* __restrict__ q1p,
    unsigned char* __restrict__ q2p,
    float* __restrict__ scales)
{
  const int b   = blockIdx.x;
  const int tid = threadIdx.x;
  const float* xr = x + (size_t)b * IN_DIM + tid * 32;

  float v[32];
  float m = 0.0f;
#pragma unroll
  for (int i = 0; i < 8; ++i) {
    float4 f = ((const float4*)xr)[i];
    v[i*4+0] = f.x; v[i*4+1] = f.y; v[i*4+2] = f.z; v[i*4+3] = f.w;
    m = fmaxf(m, fmaxf(fmaxf(fabsf(f.x), fabsf(f.y)), fmaxf(fabsf(f.z), fabsf(f.w))));
  }
#pragma unroll
  for (int off = 32; off >= 1; off >>= 1)
    m = fmaxf(m, __shfl_xor(m, off));
  __shared__ float lmax[4];
  if ((tid & 63) == 0) lmax[tid >> 6] = m;
  __syncthreads();
  m = fmaxf(fmaxf(lmax[0], lmax[1]), fmaxf(lmax[2], lmax[3]));
  m = fmaxf(m, 1e-20f);

  const float s1   = m * (1.0f / 127.0f);
  const float inv1 = 1.0f / s1;
  const float s2   = s1 * (1.0f / 254.0f);
  const float inv2 = 1.0f / s2;
  if (tid == 0) { scales[b] = s1; scales[16 + b] = s2; }

  const int kk = tid >> 1, h2 = tid & 1;
  unsigned char* b1 = q1p + kk * 1024 + b * 16 + h2 * 8;
  unsigned char* b2 = q2p + kk * 1024 + b * 16 + h2 * 8;
#pragma unroll
  for (int i16 = 0; i16 < 2; ++i16) {
#pragma unroll
    for (int grp = 0; grp < 4; ++grp) {
      unsigned a1 = 0, a2 = 0;
#pragma unroll
      for (int j = 0; j < 4; ++j) {
        const float xv = v[i16*16 + grp*4 + j];
        float q1 = rintf(xv * inv1);
        q1 = fminf(127.0f, fmaxf(-127.0f, q1));
        const float r = fmaf(-s1, q1, xv);
        float q2 = rintf(r * inv2);
        q2 = fminf(127.0f, fmaxf(-127.0f, q2));
        a1 |= ((unsigned)((int)q1 & 0xff)) << (8*j);
        a2 |= ((unsigned)((int)q2 & 0xff)) << (8*j);
      }
      *(unsigned*)(b1 + grp*256 + i16*4) = a1;
      *(unsigned*)(b2 + grp*256 + i16*4) = a2;
    }
  }
}

// issue the 16 weight loads of one super-step: 1KB contiguous per row, ascending
// addresses (plain loads — R5 showed the bundle with nt regressed; isolating)
static __device__ __forceinline__ void issue_w(v4i (&dst)[16], const char* wpb, int s) {
  const char* bp = wpb + (size_t)s * 1024;
#pragma unroll
  for (int kk2 = 0; kk2 < 4; ++kk2)
#pragma unroll
    for (int p = 0; p < 4; ++p)
      dst[kk2*4 + p] = *(const v4i*)(bp + kk2*256 + p*64);
}

static __device__ __forceinline__ void compute_ss(
    const v4i (&src)[16], int s,
    const unsigned char* x1p, const unsigned char* x2p,
    v4i& acc1, v4i& acc2) {
#pragma unroll
  for (int kk2 = 0; kk2 < 4; ++kk2) {
    const int kk = s*4 + kk2;
    const v4i xa = *(const v4i*)(x1p + (size_t)kk * 1024);
    const v4i xb = *(const v4i*)(x2p + (size_t)kk * 1024);
    v4i bw;
    bw.x = (int)pack_lo_bytes(src[kk2*4 + 0]);
    bw.y = (int)pack_lo_bytes(src[kk2*4 + 1]);
    bw.z = (int)pack_lo_bytes(src[kk2*4 + 2]);
    bw.w = (int)pack_lo_bytes(src[kk2*4 + 3]);
    acc1 = __builtin_amdgcn_mfma_i32_16x16x64_i8(xa, bw, acc1, 0, 0, 0);
    acc2 = __builtin_amdgcn_mfma_i32_16x16x64_i8(xb, bw, acc2, 0, 0, 0);
  }
}

// ---- main GEMM: 256 blocks x 7 waves; wave = 16 output channels over full K ----
// 3-buffer register rotation: 3KB/row window, ~2KB steady-state in flight.
__global__ __launch_bounds__(448, 2) void qgemm_kernel(
    const int* __restrict__ w,
    const unsigned char* __restrict__ q1p,
    const unsigned char* __restrict__ q2p,
    const float* __restrict__ scales,
    const float* __restrict__ wscaler,
    float* __restrict__ out)
{
  const int lane = threadIdx.x & 63;
  const int wv   = threadIdx.x >> 6;        // 0..6
  const int col  = lane & 15;
  const int grp  = lane >> 4;
  const int o    = blockIdx.x * 112 + wv * 16 + col;

  const char* wpb = (const char*)(w + (size_t)o * IN_DIM) + grp * 16;
  const unsigned char* x1p = q1p + lane * 16;
  const unsigned char* x2p = q2p + lane * 16;

  v4i acc1 = {0,0,0,0}, acc2 = {0,0,0,0};
  v4i wa[16], wb[16], wc[16];

  issue_w(wa, wpb, 0);
  issue_w(wb, wpb, 1);
  issue_w(wc, wpb, 2);

  for (int j = 0; j < 9; ++j) {
    const int s = j * 3;
    compute_ss(wa, s,     x1p, x2p, acc1, acc2);  issue_w(wa, wpb, s + 3);
    compute_ss(wb, s + 1, x1p, x2p, acc1, acc2);  issue_w(wb, wpb, s + 4);
    compute_ss(wc, s + 2, x1p, x2p, acc1, acc2);  issue_w(wc, wpb, s + 5);
  }
  compute_ss(wa, 27, x1p, x2p, acc1, acc2);  issue_w(wa, wpb, 30);
  compute_ss(wb, 28, x1p, x2p, acc1, acc2);  issue_w(wb, wpb, 31);
  compute_ss(wc, 29, x1p, x2p, acc1, acc2);
  compute_ss(wa, 30, x1p, x2p, acc1, acc2);
  compute_ss(wb, 31, x1p, x2p, acc1, acc2);

  // epilogue: C/D layout col=lane&15, row=(lane>>4)*4+reg
  const float sc = wscaler[o];
#pragma unroll
  for (int r = 0; r < 4; ++r) {
    const int b = grp * 4 + r;
    const float val = scales[b] * (float)acc1[r] + scales[16 + b] * (float)acc2[r];
    out[(size_t)b * OUT_DIM + o] = val * sc;
  }
}

extern "C" void kernel_launch(void* const* d_in, const int* in_sizes, int n_in,
                              void* d_out, int out_size, void* d_ws, size_t ws_size,
                              hipStream_t stream) {
  const float* x       = (const float*)d_in[0];
  const int*   w       = (const int*)d_in[1];     // int8 values stored as int32
  const float* wscaler = (const float*)d_in[2];
  float* out = (float*)d_out;

  unsigned char* ws  = (unsigned char*)d_ws;
  unsigned char* q1p = ws;                        // 128 KiB
  unsigned char* q2p = ws + 131072;               // 128 KiB
  float* scales      = (float*)(ws + 262144);     // 32 floats

  xquant_kernel<<<16, 256, 0, stream>>>(x, q1p, q2p, scales);
  qgemm_kernel<<<256, 448, 0, stream>>>(w, q1p, q2p, scales, wscaler, out);
}

// Round 7
// 170.087 us; speedup vs baseline: 1.2687x; 1.0255x over previous
//
#include <hip/hip_runtime.h>

typedef int v4i __attribute__((ext_vector_type(4)));

#define B_DIM   16
#define IN_DIM  8192
#define OUT_DIM 28672
#define NKS     128             // k-steps of K=64 int8
#define NS      32              // super-steps (4 k-steps = 1KB/row each)

// pack low bytes of 4 int32 lanes -> one dword (3x v_perm_b32)
static __device__ __forceinline__ unsigned pack_lo_bytes(v4i q) {
  unsigned t0 = __builtin_amdgcn_perm((unsigned)q.y, (unsigned)q.x, 0x00000400u);
  unsigned t1 = __builtin_amdgcn_perm((unsigned)q.w, (unsigned)q.z, 0x00000400u);
  return __builtin_amdgcn_perm(t1, t0, 0x05040100u);
}

// ---- pre-pass: per-row 2-level int8 quantization of x, packed in MFMA A-fragment order ----
// k = kk*64 + d*16 + grp*4 + j lives at kk*1024 + grp*256 + b*16 + d*4 + j.
// B-side uses the same (grp,d,j)->k map, so the MFMA k-slot permutation cancels exactly.
__global__ __launch_bounds__(256) void xquant_kernel(
    const float* __restrict__ x,
    unsigned char* __restrict__ q1p,
    unsigned char* __restrict__ q2p,
    float* __restrict__ scales)
{
  const int b   = blockIdx.x;
  const int tid = threadIdx.x;
  const float* xr = x + (size_t)b * IN_DIM + tid * 32;

  float v[32];
  float m = 0.0f;
#pragma unroll
  for (int i = 0; i < 8; ++i) {
    float4 f = ((const float4*)xr)[i];
    v[i*4+0] = f.x; v[i*4+1] = f.y; v[i*4+2] = f.z; v[i*4+3] = f.w;
    m = fmaxf(m, fmaxf(fmaxf(fabsf(f.x), fabsf(f.y)), fmaxf(fabsf(f.z), fabsf(f.w))));
  }
#pragma unroll
  for (int off = 32; off >= 1; off >>= 1)
    m = fmaxf(m, __shfl_xor(m, off));
  __shared__ float lmax[4];
  if ((tid & 63) == 0) lmax[tid >> 6] = m;
  __syncthreads();
  m = fmaxf(fmaxf(lmax[0], lmax[1]), fmaxf(lmax[2], lmax[3]));
  m = fmaxf(m, 1e-20f);

  const float s1   = m * (1.0f / 127.0f);
  const float inv1 = 1.0f / s1;
  const float s2   = s1 * (1.0f / 254.0f);
  const float inv2 = 1.0f / s2;
  if (tid == 0) { scales[b] = s1; scales[16 + b] = s2; }

  const int kk = tid >> 1, h2 = tid & 1;
  unsigned char* b1 = q1p + kk * 1024 + b * 16 + h2 * 8;
  unsigned char* b2 = q2p + kk * 1024 + b * 16 + h2 * 8;
#pragma unroll
  for (int i16 = 0; i16 < 2; ++i16) {
#pragma unroll
    for (int grp = 0; grp < 4; ++grp) {
      unsigned a1 = 0, a2 = 0;
#pragma unroll
      for (int j = 0; j < 4; ++j) {
        const float xv = v[i16*16 + grp*4 + j];
        float q1 = rintf(xv * inv1);
        q1 = fminf(127.0f, fmaxf(-127.0f, q1));
        const float r = fmaf(-s1, q1, xv);
        float q2 = rintf(r * inv2);
        q2 = fminf(127.0f, fmaxf(-127.0f, q2));
        a1 |= ((unsigned)((int)q1 & 0xff)) << (8*j);
        a2 |= ((unsigned)((int)q2 & 0xff)) << (8*j);
      }
      *(unsigned*)(b1 + grp*256 + i16*4) = a1;
      *(unsigned*)(b2 + grp*256 + i16*4) = a2;
    }
  }
}

// issue the 16 weight loads of one super-step: 1KB contiguous per row, ascending addresses
static __device__ __forceinline__ void issue_w(v4i (&dst)[16], const char* wpb, int s) {
  const char* bp = wpb + (size_t)s * 1024;
#pragma unroll
  for (int kk2 = 0; kk2 < 4; ++kk2)
#pragma unroll
    for (int p = 0; p < 4; ++p)
      dst[kk2*4 + p] = *(const v4i*)(bp + kk2*256 + p*64);
}

static __device__ __forceinline__ void compute_ss(
    const v4i (&src)[16], int s,
    const unsigned char* x1p, const unsigned char* x2p,
    v4i& acc1, v4i& acc2) {
#pragma unroll
  for (int kk2 = 0; kk2 < 4; ++kk2) {
    const int kk = s*4 + kk2;
    const v4i xa = *(const v4i*)(x1p + (size_t)kk * 1024);
    const v4i xb = *(const v4i*)(x2p + (size_t)kk * 1024);
    v4i bw;
    bw.x = (int)pack_lo_bytes(src[kk2*4 + 0]);
    bw.y = (int)pack_lo_bytes(src[kk2*4 + 1]);
    bw.z = (int)pack_lo_bytes(src[kk2*4 + 2]);
    bw.w = (int)pack_lo_bytes(src[kk2*4 + 3]);
    acc1 = __builtin_amdgcn_mfma_i32_16x16x64_i8(xa, bw, acc1, 0, 0, 0);
    acc2 = __builtin_amdgcn_mfma_i32_16x16x64_i8(xb, bw, acc2, 0, 0, 0);
  }
}

// ---- main GEMM: 256 blocks x 7 waves; wave = 16 output channels over full K ----
__global__ __launch_bounds__(448, 2) void qgemm_kernel(
    const int* __restrict__ w,
    const unsigned char* __restrict__ q1p,
    const unsigned char* __restrict__ q2p,
    const float* __restrict__ scales,
    const float* __restrict__ wscaler,
    float* __restrict__ out)
{
  const int lane = threadIdx.x & 63;
  const int wv   = threadIdx.x >> 6;        // 0..6
  const int col  = lane & 15;
  const int grp  = lane >> 4;
  const int o    = blockIdx.x * 112 + wv * 16 + col;

  const char* wpb = (const char*)(w + (size_t)o * IN_DIM) + grp * 16;
  const unsigned char* x1p = q1p + lane * 16;
  const unsigned char* x2p = q2p + lane * 16;

  v4i acc1 = {0,0,0,0}, acc2 = {0,0,0,0};
  v4i wa[16], wb2[16];

  issue_w(wa, wpb, 0);
  for (int s = 0; s < NS; s += 2) {
    issue_w(wb2, wpb, s + 1);
    compute_ss(wa,  s,     x1p, x2p, acc1, acc2);
    if (s + 2 < NS) issue_w(wa, wpb, s + 2);
    compute_ss(wb2, s + 1, x1p, x2p, acc1, acc2);
  }

  // epilogue: C/D layout col=lane&15, row=(lane>>4)*4+reg
  const float sc = wscaler[o];
#pragma unroll
  for (int r = 0; r < 4; ++r) {
    const int b = grp * 4 + r;
    const float val = scales[b] * (float)acc1[r] + scales[16 + b] * (float)acc2[r];
    out[(size_t)b * OUT_DIM + o] = val * sc;
  }
}

extern "C" void kernel_launch(void* const* d_in, const int* in_sizes, int n_in,
                              void* d_out, int out_size, void* d_ws, size_t ws_size,
                              hipStream_t stream) {
  const float* x       = (const float*)d_in[0];
  const int*   w       = (const int*)d_in[1];
  const float* wscaler = (const float*)d_in[2];
  float* out = (float*)d_out;

  unsigned char* ws  = (unsigned char*)d_ws;
  unsigned char* q1p = ws;                        // 128 KiB
  unsigned char* q2p = ws + 131072;               // 128 KiB
  float* scales      = (float*)(ws + 262144);     // 32 floats

  xquant_kernel<<<16, 256, 0, stream>>>(x, q1p, q2p, scales);
  qgemm_kernel<<<256, 448, 0, stream>>>(w, q1p, q2p, scales, wscaler, out);
}